// Round 8
// baseline (27995.682 us; speedup 1.0000x reference)
//
#include <hip/hip_runtime.h>

#define TT   2048
#define NB   32
#define NI   512
#define NHID 512
#define NWG  32
#define KSL  16   // h-columns owned per workgroup

typedef float    f32x4 __attribute__((ext_vector_type(4)));
typedef float    f32x2 __attribute__((ext_vector_type(2)));
typedef _Float16 f16x8 __attribute__((ext_vector_type(8)));

// Handshake state in ordinary device memory (module-scope globals).
__device__ __align__(256) unsigned int g_flags[64];
__device__ __align__(256) _Float16    g_hb0[NB * NHID];
__device__ __align__(256) _Float16    g_hb1[NB * NHID];

__device__ __forceinline__ f16x8 pack8(f32x4 a, f32x4 b) {
    f16x8 r;
    r[0] = (_Float16)a[0]; r[1] = (_Float16)a[1]; r[2] = (_Float16)a[2]; r[3] = (_Float16)a[3];
    r[4] = (_Float16)b[0]; r[5] = (_Float16)b[1]; r[6] = (_Float16)b[2]; r[7] = (_Float16)b[3];
    return r;
}

// nt load: never allocates in L1 -> always served by the (XCD-shared) L2.
__device__ __forceinline__ unsigned int poll_load_nt(const unsigned int* p) {
    unsigned int v;
    asm volatile("global_load_dword %0, %1, off nt\n\ts_waitcnt vmcnt(0)"
                 : "=v"(v) : "v"(p) : "memory");
    return v;
}

extern "C" __global__ void init_flags_k() {
    if (threadIdx.x < 64) g_flags[threadIdx.x] = 0u;
}

// Persistent GRU: 512 blocks. Workers = bid<256 && bid%8==0 (all on XCD0 if the
// round-robin bid%8->XCD mapping holds; verified at runtime via HW_REG_XCC_ID).
// The other 480 blocks are DVFS spinners: 4 waves of dense FMA on EVERY XCD
// including co-resident on the worker CUs (512 blocks = exactly 2 blocks/CU:
// VGPR 2x256=512/SIMD, LDS 2x16.9KB). Evidence for low clock: VALUBusy and
// MfmaUtil both back-solve to ~8000 cy/step at 9.4us/step => ~0.85 GHz.
// Workers run at s_setprio(1) so spinner issue never delays the critical path.
extern "C" __global__ void __launch_bounds__(256, 2)
gru_persist(const float* __restrict__ X, const float* __restrict__ h0,
            const float* __restrict__ Wih, const float* __restrict__ Whh,
            const float* __restrict__ bih, const float* __restrict__ bhh,
            const float* __restrict__ Wd,  const float* __restrict__ bd,
            float* __restrict__ out)
{
    unsigned int* flags = g_flags;
    unsigned int* mask  = g_flags + 32;
    unsigned int* count = g_flags + 33;
    unsigned int* done  = g_flags + 34;

    const bool is_worker = (blockIdx.x < 256) && ((blockIdx.x & 7) == 0);

    if (!is_worker) {
        // ---- DVFS spinner: 4 waves of dense independent FMA until done.
        float a0 = 1.0f + (float)threadIdx.x, a1 = a0 + 0.1f, a2 = a0 + 0.2f, a3 = a0 + 0.3f;
        float a4 = a0 + 0.4f, a5 = a0 + 0.5f, a6 = a0 + 0.6f, a7 = a0 + 0.7f;
        const float m = 1.0000001f, c = 1.0e-7f;
        while (__hip_atomic_load(done, __ATOMIC_RELAXED,
                                 __HIP_MEMORY_SCOPE_AGENT) == 0u) {
            #pragma unroll 32
            for (int i = 0; i < 2048; ++i) {
                a0 = __builtin_fmaf(a0, m, c); a1 = __builtin_fmaf(a1, m, c);
                a2 = __builtin_fmaf(a2, m, c); a3 = __builtin_fmaf(a3, m, c);
                a4 = __builtin_fmaf(a4, m, c); a5 = __builtin_fmaf(a5, m, c);
                a6 = __builtin_fmaf(a6, m, c); a7 = __builtin_fmaf(a7, m, c);
            }
            asm volatile("" :: "v"(a0), "v"(a1), "v"(a2), "v"(a3),
                              "v"(a4), "v"(a5), "v"(a6), "v"(a7));
        }
        return;
    }

    __builtin_amdgcn_s_setprio(1);       // workers outrank spinners on shared SIMDs
    const int w = blockIdx.x >> 3;       // worker id 0..31

    __shared__ float C_lds[7][NB][KSL];  // 0..2 gh(r,z,n), 3..5 gi(r,z,n), 6 dense
    __shared__ float h_lds[NB][KSL];     // f32 master copy of own h slice
    __shared__ float bias_lds[7][KSL];
    __shared__ unsigned int fast_sh;

    const int ks   = w * KSL;
    const int tid  = threadIdx.x;
    const int lane = tid & 63;
    const int wv   = tid >> 6;
    const int bt   = wv & 1;    // batch tile (rows bt*16 .. +16)
    const int jg   = wv >> 1;   // 0 = hidden side, 1 = input side
    const int r15  = lane & 15;
    const int g4   = lane >> 4;

    // ---- one-time init: biases + own h slice into LDS
    if (tid < KSL) {
        int k = ks + tid;
        bias_lds[0][tid] = bhh[k];
        bias_lds[1][tid] = bhh[512 + k];
        bias_lds[2][tid] = bhh[1024 + k];
        bias_lds[3][tid] = bih[k];
        bias_lds[4][tid] = bih[512 + k];
        bias_lds[5][tid] = bih[1024 + k];
        bias_lds[6][tid] = bd[k];
    }
    {
        int idx = tid * 2;
        int b = idx >> 4, kl = idx & 15;
        f32x2 hv = *(const f32x2*)(h0 + (size_t)b * NHID + ks + kl);
        h_lds[b][kl]     = hv[0];
        h_lds[b][kl + 1] = hv[1];
    }

    // ---- one-time: weight A-fragments into registers (fp16):
    // A[q][kc]: lane holds W[row_base + (lane&15)][kc*32 + (lane>>4)*8 + e], e=0..7
    f16x8 A[4][16];
    {
        const float* m0 = (jg == 0) ? Whh : Wih;
        #pragma unroll
        for (int q = 0; q < 4; ++q) {
            const float* src;
            if (q < 3) src = m0 + (size_t)(q * 512 + ks + r15) * NI;
            else       src = (jg == 0) ? (m0 + (size_t)(1024 + ks + r15) * NI)   // dup (unused)
                                       : (Wd + (size_t)(ks + r15) * NI);
            #pragma unroll
            for (int kc = 0; kc < 16; ++kc) {
                const f32x4* p = (const f32x4*)(src + kc * 32 + g4 * 8);
                A[q][kc] = pack8(p[0], p[1]);
            }
        }
    }

    // ---- placement check: fast iff all 32 workers share one XCD
    if (tid == 0) {
        unsigned int xcc;
        asm volatile("s_getreg_b32 %0, hwreg(HW_REG_XCC_ID, 0, 32)" : "=s"(xcc));
        unsigned int bit = 1u << (xcc & 7);
        unsigned int old = __hip_atomic_fetch_or(mask, bit, __ATOMIC_RELAXED,
                                                 __HIP_MEMORY_SCOPE_AGENT);
        asm volatile("" :: "v"(old));   // force OR-ack before the ADD below
        __hip_atomic_fetch_add(count, 1u, __ATOMIC_RELAXED, __HIP_MEMORY_SCOPE_AGENT);
        while (__hip_atomic_load(count, __ATOMIC_RELAXED,
                                 __HIP_MEMORY_SCOPE_AGENT) < NWG) { }
        unsigned int m = __hip_atomic_load(mask, __ATOMIC_RELAXED,
                                           __HIP_MEMORY_SCOPE_AGENT);
        fast_sh = ((m & (m - 1)) == 0) ? 1u : 0u;
    }
    __syncthreads();
    const bool fast = (fast_sh != 0);

    const float* Xrow  = X  + (size_t)(bt * 16 + r15) * NI;
    const float* h0row = h0 + (size_t)(bt * 16 + r15) * NHID;
    const size_t hoff  = (size_t)(bt * 16 + r15) * NHID;

    #pragma unroll 1
    for (int t = 0; t < TT; ++t) {
        // ---- Phase A: input-side projections for step t (waves 2,3)
        if (jg == 1) {
            const float* xp = Xrow + (size_t)t * (NB * NI);
            f16x8 Bf[16];
            #pragma unroll
            for (int kc = 0; kc < 16; ++kc) {
                const f32x4* p = (const f32x4*)(xp + kc * 32 + g4 * 8);
                Bf[kc] = pack8(p[0], p[1]);
            }
            f32x4 acc[4];
            #pragma unroll
            for (int q = 0; q < 4; ++q) acc[q] = (f32x4){0.f, 0.f, 0.f, 0.f};
            #pragma unroll
            for (int kc = 0; kc < 16; ++kc) {
                #pragma unroll
                for (int q = 0; q < 4; ++q)
                    acc[q] = __builtin_amdgcn_mfma_f32_16x16x32_f16(A[q][kc], Bf[kc], acc[q], 0, 0, 0);
            }
            #pragma unroll
            for (int q = 0; q < 4; ++q)
                *(f32x4*)&C_lds[3 + q][bt * 16 + r15][g4 * 4] = acc[q];
        }

        // ---- Phase B: wait for all h_t slices
        if (t > 0 && tid < NWG) {
            if (fast) {
                while (poll_load_nt(&flags[tid]) < (unsigned)t) { }
            } else {
                while (__hip_atomic_load(&flags[tid], __ATOMIC_RELAXED,
                                         __HIP_MEMORY_SCOPE_AGENT) < (unsigned)t) { }
            }
        }
        __syncthreads();

        // ---- Phase C: hidden-side gh (waves 0,1) — the critical path
        if (jg == 0) {
            f16x8 Bf[16];
            if (t == 0) {
                #pragma unroll
                for (int kc = 0; kc < 16; ++kc) {
                    const f32x4* p = (const f32x4*)(h0row + kc * 32 + g4 * 8);
                    Bf[kc] = pack8(p[0], p[1]);
                }
            } else if (fast) {
                const _Float16* hrow = ((t & 1) ? g_hb1 : g_hb0) + hoff;
                #pragma unroll
                for (int kc = 0; kc < 16; ++kc) {
                    const _Float16* p = hrow + kc * 32 + g4 * 8;
                    asm volatile("global_load_dwordx4 %0, %1, off nt"
                                 : "=v"(Bf[kc]) : "v"(p));
                }
                asm volatile("s_waitcnt vmcnt(0)" ::: "memory");
                __builtin_amdgcn_sched_barrier(0);
            } else {
                const _Float16* hrow = ((t & 1) ? g_hb1 : g_hb0) + hoff;
                #pragma unroll
                for (int kc = 0; kc < 16; ++kc) {
                    union { unsigned long long u[2]; f16x8 v; } cv;
                    const unsigned long long* p =
                        (const unsigned long long*)(hrow + kc * 32 + g4 * 8);
                    cv.u[0] = __hip_atomic_load(p,     __ATOMIC_RELAXED, __HIP_MEMORY_SCOPE_AGENT);
                    cv.u[1] = __hip_atomic_load(p + 1, __ATOMIC_RELAXED, __HIP_MEMORY_SCOPE_AGENT);
                    Bf[kc] = cv.v;
                }
            }
            f32x4 acc[3];
            #pragma unroll
            for (int q = 0; q < 3; ++q) acc[q] = (f32x4){0.f, 0.f, 0.f, 0.f};
            #pragma unroll
            for (int kc = 0; kc < 16; ++kc) {
                #pragma unroll
                for (int q = 0; q < 3; ++q)
                    acc[q] = __builtin_amdgcn_mfma_f32_16x16x32_f16(A[q][kc], Bf[kc], acc[q], 0, 0, 0);
            }
            #pragma unroll
            for (int q = 0; q < 3; ++q)
                *(f32x4*)&C_lds[q][bt * 16 + r15][g4 * 4] = acc[q];
        }
        __syncthreads();

        // ---- Phase E: fused gates (f32), h update
        int   idx = tid * 2;
        int   b   = idx >> 4, kl = idx & 15;
        float o2[2];
        {
            float hn2[2];
            #pragma unroll
            for (int e = 0; e < 2; ++e) {
                int k = kl + e;
                float ghr = C_lds[0][b][k] + bias_lds[0][k];
                float ghz = C_lds[1][b][k] + bias_lds[1][k];
                float ghn = C_lds[2][b][k] + bias_lds[2][k];
                float gir = C_lds[3][b][k] + bias_lds[3][k];
                float giz = C_lds[4][b][k] + bias_lds[4][k];
                float gin = C_lds[5][b][k] + bias_lds[5][k];
                float dns = C_lds[6][b][k] + bias_lds[6][k];
                float rr = 1.f / (1.f + __expf(-(gir + ghr)));
                float zz = 1.f / (1.f + __expf(-(giz + ghz)));
                float aa = gin + rr * ghn;
                float nn = 1.f - 2.f / (__expf(2.f * aa) + 1.f);   // tanh(aa)
                float hold = h_lds[b][k];
                float hn = (1.f - zz) * nn + zz * hold;
                h_lds[b][k] = hn;
                hn2[e] = hn;
                o2[e] = hn + dns;
            }
            // h_{t+1} broadcast into parity buffer (t+1)&1
            _Float16* hw = (((t + 1) & 1) ? g_hb1 : g_hb0);
            union { _Float16 hh[2]; unsigned int u; } cv;
            cv.hh[0] = (_Float16)hn2[0]; cv.hh[1] = (_Float16)hn2[1];
            unsigned int* hp = (unsigned int*)(hw + (size_t)b * NHID + ks + kl);
            if (fast) *hp = cv.u;  // write-through L1 -> shared L2
            else __hip_atomic_store(hp, cv.u, __ATOMIC_RELAXED, __HIP_MEMORY_SCOPE_AGENT);
        }
        // per-wave: our h stores acked (in L2 / at coherence point) before barrier
        asm volatile("s_waitcnt vmcnt(0)" ::: "memory");
        __syncthreads();

        // ---- Phase F: publish h_{t+1}
        if (tid == 0) {
            if (fast) ((volatile unsigned int*)flags)[w] = (unsigned)(t + 1);
            else __hip_atomic_store(&flags[w], (unsigned)(t + 1), __ATOMIC_RELAXED,
                                    __HIP_MEMORY_SCOPE_AGENT);
        }

        // ---- deferred output write (drains during next step's wait)
        {
            f32x2 ov = { o2[0], o2[1] };
            *(f32x2*)&out[(size_t)t * (NB * NHID) + (size_t)b * NHID + ks + kl] = ov;
        }
    }

    // ---- h_last output
    {
        int idx = tid * 2;
        int b = idx >> 4, kl = idx & 15;
        float* hl = out + (size_t)TT * NB * NHID;
        f32x2 hv = { h_lds[b][kl], h_lds[b][kl + 1] };
        *(f32x2*)&hl[(size_t)b * NHID + ks + kl] = hv;
    }

    // ---- release the spinner blocks
    if (w == 0 && tid == 0) {
        __hip_atomic_store(done, 1u, __ATOMIC_RELAXED, __HIP_MEMORY_SCOPE_AGENT);
    }
}

extern "C" void kernel_launch(void* const* d_in, const int* in_sizes, int n_in,
                              void* d_out, int out_size, void* d_ws, size_t ws_size,
                              hipStream_t stream) {
    const float* X   = (const float*)d_in[0];
    const float* h0  = (const float*)d_in[1];
    const float* Wih = (const float*)d_in[2];
    const float* Whh = (const float*)d_in[3];
    const float* bih = (const float*)d_in[4];
    const float* bhh = (const float*)d_in[5];
    const float* Wd  = (const float*)d_in[6];
    const float* bd  = (const float*)d_in[7];
    float* out = (float*)d_out;

    init_flags_k<<<dim3(1), dim3(64), 0, stream>>>();

    gru_persist<<<dim3(512), dim3(256), 0, stream>>>(
        X, h0, Wih, Whh, bih, bhh, Wd, bd, out);
}

// Round 9
// 18873.296 us; speedup vs baseline: 1.4833x; 1.4833x over previous
//
#include <hip/hip_runtime.h>

#define TT   2048
#define NB   32
#define NI   512
#define NHID 512
#define NWG  32
#define KSL  16   // h-columns owned per workgroup

typedef float    f32x4 __attribute__((ext_vector_type(4)));
typedef float    f32x2 __attribute__((ext_vector_type(2)));
typedef _Float16 f16x8 __attribute__((ext_vector_type(8)));

// Handshake state in ordinary device memory (module-scope globals).
__device__ __align__(256) unsigned int g_flags[64];
__device__ __align__(256) _Float16    g_hb0[NB * NHID];
__device__ __align__(256) _Float16    g_hb1[NB * NHID];

__device__ __forceinline__ f16x8 pack8(f32x4 a, f32x4 b) {
    f16x8 r;
    r[0] = (_Float16)a[0]; r[1] = (_Float16)a[1]; r[2] = (_Float16)a[2]; r[3] = (_Float16)a[3];
    r[4] = (_Float16)b[0]; r[5] = (_Float16)b[1]; r[6] = (_Float16)b[2]; r[7] = (_Float16)b[3];
    return r;
}

// nt load: never allocates in L1 -> always served by the (XCD-shared) L2.
__device__ __forceinline__ unsigned int poll_load_nt(const unsigned int* p) {
    unsigned int v;
    asm volatile("global_load_dword %0, %1, off nt\n\ts_waitcnt vmcnt(0)"
                 : "=v"(v) : "v"(p) : "memory");
    return v;
}

extern "C" __global__ void init_flags_k() {
    if (threadIdx.x < 64) g_flags[threadIdx.x] = 0u;
}

// Persistent GRU: 256 blocks, workers = bid%8==0 (all on XCD0 if round-robin
// bid%8->XCD holds; verified at runtime), others exit. SINGLE CHANGE vs round 7:
// during the flag wait, waves 1-3 spin dense FMA chains (prio 0) gated by an LDS
// ready flag -> all 32 worker CUs show sustained VALU activity -> per-XCD DPM
// stimulus for XCD0 itself (round 8's spinners never touched XCD0 and also
// VGPR-capped the workers to 128 -> spills; both fixed here).
// Evidence for low clock: MfmaUtil and VALUBusy independently back-solve to
// ~8100 actual cycles/step at 9.4us/step => SCLK ~0.86 GHz.
extern "C" __global__ void __launch_bounds__(256, 1)
gru_persist(const float* __restrict__ X, const float* __restrict__ h0,
            const float* __restrict__ Wih, const float* __restrict__ Whh,
            const float* __restrict__ bih, const float* __restrict__ bhh,
            const float* __restrict__ Wd,  const float* __restrict__ bd,
            float* __restrict__ out)
{
    if (blockIdx.x & 7) return;          // non-workers exit immediately
    const int w = blockIdx.x >> 3;       // worker id 0..31

    __shared__ float C_lds[7][NB][KSL];  // 0..2 gh(r,z,n), 3..5 gi(r,z,n), 6 dense
    __shared__ float h_lds[NB][KSL];     // f32 master copy of own h slice
    __shared__ float bias_lds[7][KSL];
    __shared__ unsigned int fast_sh;
    __shared__ unsigned int ready_sh;    // step whose h is known globally visible

    unsigned int* flags = g_flags;
    unsigned int* mask  = g_flags + 32;
    unsigned int* count = g_flags + 33;

    const int ks   = w * KSL;
    const int tid  = threadIdx.x;
    const int lane = tid & 63;
    const int wv   = tid >> 6;
    const int bt   = wv & 1;    // batch tile (rows bt*16 .. +16)
    const int jg   = wv >> 1;   // 0 = hidden side, 1 = input side
    const int r15  = lane & 15;
    const int g4   = lane >> 4;

    __builtin_amdgcn_s_setprio(1);       // critical-path waves outrank spinners

    // ---- one-time init: biases + own h slice into LDS
    if (tid == 0) ready_sh = 0u;
    if (tid < KSL) {
        int k = ks + tid;
        bias_lds[0][tid] = bhh[k];
        bias_lds[1][tid] = bhh[512 + k];
        bias_lds[2][tid] = bhh[1024 + k];
        bias_lds[3][tid] = bih[k];
        bias_lds[4][tid] = bih[512 + k];
        bias_lds[5][tid] = bih[1024 + k];
        bias_lds[6][tid] = bd[k];
    }
    {
        int idx = tid * 2;
        int b = idx >> 4, kl = idx & 15;
        f32x2 hv = *(const f32x2*)(h0 + (size_t)b * NHID + ks + kl);
        h_lds[b][kl]     = hv[0];
        h_lds[b][kl + 1] = hv[1];
    }

    // ---- one-time: weight A-fragments into registers (fp16):
    // A[q][kc]: lane holds W[row_base + (lane&15)][kc*32 + (lane>>4)*8 + e], e=0..7
    f16x8 A[4][16];
    {
        const float* m0 = (jg == 0) ? Whh : Wih;
        #pragma unroll
        for (int q = 0; q < 4; ++q) {
            const float* src;
            if (q < 3) src = m0 + (size_t)(q * 512 + ks + r15) * NI;
            else       src = (jg == 0) ? (m0 + (size_t)(1024 + ks + r15) * NI)   // dup (unused)
                                       : (Wd + (size_t)(ks + r15) * NI);
            #pragma unroll
            for (int kc = 0; kc < 16; ++kc) {
                const f32x4* p = (const f32x4*)(src + kc * 32 + g4 * 8);
                A[q][kc] = pack8(p[0], p[1]);
            }
        }
    }

    // ---- placement check: fast iff all 32 workers share one XCD
    if (tid == 0) {
        unsigned int xcc;
        asm volatile("s_getreg_b32 %0, hwreg(HW_REG_XCC_ID, 0, 32)" : "=s"(xcc));
        unsigned int bit = 1u << (xcc & 7);
        unsigned int old = __hip_atomic_fetch_or(mask, bit, __ATOMIC_RELAXED,
                                                 __HIP_MEMORY_SCOPE_AGENT);
        asm volatile("" :: "v"(old));   // force OR-ack before the ADD below
        __hip_atomic_fetch_add(count, 1u, __ATOMIC_RELAXED, __HIP_MEMORY_SCOPE_AGENT);
        while (__hip_atomic_load(count, __ATOMIC_RELAXED,
                                 __HIP_MEMORY_SCOPE_AGENT) < NWG) { }
        unsigned int m = __hip_atomic_load(mask, __ATOMIC_RELAXED,
                                           __HIP_MEMORY_SCOPE_AGENT);
        fast_sh = ((m & (m - 1)) == 0) ? 1u : 0u;
    }
    __syncthreads();
    const bool fast = (fast_sh != 0);

    const float* Xrow  = X  + (size_t)(bt * 16 + r15) * NI;
    const float* h0row = h0 + (size_t)(bt * 16 + r15) * NHID;
    const size_t hoff  = (size_t)(bt * 16 + r15) * NHID;

    #pragma unroll 1
    for (int t = 0; t < TT; ++t) {
        // ---- Phase A: input-side projections for step t (waves 2,3)
        if (jg == 1) {
            const float* xp = Xrow + (size_t)t * (NB * NI);
            f16x8 Bf[16];
            #pragma unroll
            for (int kc = 0; kc < 16; ++kc) {
                const f32x4* p = (const f32x4*)(xp + kc * 32 + g4 * 8);
                Bf[kc] = pack8(p[0], p[1]);
            }
            f32x4 acc[4];
            #pragma unroll
            for (int q = 0; q < 4; ++q) acc[q] = (f32x4){0.f, 0.f, 0.f, 0.f};
            #pragma unroll
            for (int kc = 0; kc < 16; ++kc) {
                #pragma unroll
                for (int q = 0; q < 4; ++q)
                    acc[q] = __builtin_amdgcn_mfma_f32_16x16x32_f16(A[q][kc], Bf[kc], acc[q], 0, 0, 0);
            }
            #pragma unroll
            for (int q = 0; q < 4; ++q)
                *(f32x4*)&C_lds[3 + q][bt * 16 + r15][g4 * 4] = acc[q];
        }

        // ---- Phase B: wait for all h_t slices. Wave 0 polls; waves 1-3 spin
        // dense FMA chains at prio 0 (per-XCD DPM stimulus), gated by ready_sh.
        if (t > 0) {
            if (wv == 0) {
                if (lane < NWG) {
                    if (fast) {
                        while (poll_load_nt(&flags[lane]) < (unsigned)t) { }
                    } else {
                        while (__hip_atomic_load(&flags[lane], __ATOMIC_RELAXED,
                                                 __HIP_MEMORY_SCOPE_AGENT) < (unsigned)t) { }
                    }
                }
                asm volatile("" ::: "memory");      // polls retired (wave reconverged)
                if (lane == 0) *(volatile unsigned int*)&ready_sh = (unsigned)t;
            } else {
                __builtin_amdgcn_s_setprio(0);
                float s0 = 1.00f + (float)lane, s1 = s0 + .1f, s2 = s0 + .2f, s3 = s0 + .3f;
                float s4 = s0 + .4f, s5 = s0 + .5f, s6 = s0 + .6f, s7 = s0 + .7f;
                const float mm = 1.0000001f, cc = 1.0e-7f;
                while (*(volatile unsigned int*)&ready_sh < (unsigned)t) {
                    #pragma unroll
                    for (int i = 0; i < 8; ++i) {
                        s0 = __builtin_fmaf(s0, mm, cc); s1 = __builtin_fmaf(s1, mm, cc);
                        s2 = __builtin_fmaf(s2, mm, cc); s3 = __builtin_fmaf(s3, mm, cc);
                        s4 = __builtin_fmaf(s4, mm, cc); s5 = __builtin_fmaf(s5, mm, cc);
                        s6 = __builtin_fmaf(s6, mm, cc); s7 = __builtin_fmaf(s7, mm, cc);
                    }
                }
                asm volatile("" :: "v"(s0), "v"(s1), "v"(s2), "v"(s3),
                                  "v"(s4), "v"(s5), "v"(s6), "v"(s7));
                __builtin_amdgcn_s_setprio(1);
            }
        }
        __syncthreads();

        // ---- Phase C: hidden-side gh (waves 0,1) — the critical path
        if (jg == 0) {
            f16x8 Bf[16];
            if (t == 0) {
                #pragma unroll
                for (int kc = 0; kc < 16; ++kc) {
                    const f32x4* p = (const f32x4*)(h0row + kc * 32 + g4 * 8);
                    Bf[kc] = pack8(p[0], p[1]);
                }
            } else if (fast) {
                const _Float16* hrow = ((t & 1) ? g_hb1 : g_hb0) + hoff;
                #pragma unroll
                for (int kc = 0; kc < 16; ++kc) {
                    const _Float16* p = hrow + kc * 32 + g4 * 8;
                    asm volatile("global_load_dwordx4 %0, %1, off nt"
                                 : "=v"(Bf[kc]) : "v"(p));
                }
                asm volatile("s_waitcnt vmcnt(0)" ::: "memory");
                __builtin_amdgcn_sched_barrier(0);
            } else {
                const _Float16* hrow = ((t & 1) ? g_hb1 : g_hb0) + hoff;
                #pragma unroll
                for (int kc = 0; kc < 16; ++kc) {
                    union { unsigned long long u[2]; f16x8 v; } cv;
                    const unsigned long long* p =
                        (const unsigned long long*)(hrow + kc * 32 + g4 * 8);
                    cv.u[0] = __hip_atomic_load(p,     __ATOMIC_RELAXED, __HIP_MEMORY_SCOPE_AGENT);
                    cv.u[1] = __hip_atomic_load(p + 1, __ATOMIC_RELAXED, __HIP_MEMORY_SCOPE_AGENT);
                    Bf[kc] = cv.v;
                }
            }
            f32x4 acc[3];
            #pragma unroll
            for (int q = 0; q < 3; ++q) acc[q] = (f32x4){0.f, 0.f, 0.f, 0.f};
            #pragma unroll
            for (int kc = 0; kc < 16; ++kc) {
                #pragma unroll
                for (int q = 0; q < 3; ++q)
                    acc[q] = __builtin_amdgcn_mfma_f32_16x16x32_f16(A[q][kc], Bf[kc], acc[q], 0, 0, 0);
            }
            #pragma unroll
            for (int q = 0; q < 3; ++q)
                *(f32x4*)&C_lds[q][bt * 16 + r15][g4 * 4] = acc[q];
        }
        __syncthreads();

        // ---- Phase E: fused gates (f32), h update
        int   idx = tid * 2;
        int   b   = idx >> 4, kl = idx & 15;
        float o2[2];
        {
            float hn2[2];
            #pragma unroll
            for (int e = 0; e < 2; ++e) {
                int k = kl + e;
                float ghr = C_lds[0][b][k] + bias_lds[0][k];
                float ghz = C_lds[1][b][k] + bias_lds[1][k];
                float ghn = C_lds[2][b][k] + bias_lds[2][k];
                float gir = C_lds[3][b][k] + bias_lds[3][k];
                float giz = C_lds[4][b][k] + bias_lds[4][k];
                float gin = C_lds[5][b][k] + bias_lds[5][k];
                float dns = C_lds[6][b][k] + bias_lds[6][k];
                float rr = 1.f / (1.f + __expf(-(gir + ghr)));
                float zz = 1.f / (1.f + __expf(-(giz + ghz)));
                float aa = gin + rr * ghn;
                float nn = 1.f - 2.f / (__expf(2.f * aa) + 1.f);   // tanh(aa)
                float hold = h_lds[b][k];
                float hn = (1.f - zz) * nn + zz * hold;
                h_lds[b][k] = hn;
                hn2[e] = hn;
                o2[e] = hn + dns;
            }
            // h_{t+1} broadcast into parity buffer (t+1)&1
            _Float16* hw = (((t + 1) & 1) ? g_hb1 : g_hb0);
            union { _Float16 hh[2]; unsigned int u; } cv;
            cv.hh[0] = (_Float16)hn2[0]; cv.hh[1] = (_Float16)hn2[1];
            unsigned int* hp = (unsigned int*)(hw + (size_t)b * NHID + ks + kl);
            if (fast) *hp = cv.u;  // write-through L1 -> shared L2
            else __hip_atomic_store(hp, cv.u, __ATOMIC_RELAXED, __HIP_MEMORY_SCOPE_AGENT);
        }
        // per-wave: our h stores acked (in L2 / at coherence point) before barrier
        asm volatile("s_waitcnt vmcnt(0)" ::: "memory");
        __syncthreads();

        // ---- Phase F: publish h_{t+1}
        if (tid == 0) {
            if (fast) ((volatile unsigned int*)flags)[w] = (unsigned)(t + 1);
            else __hip_atomic_store(&flags[w], (unsigned)(t + 1), __ATOMIC_RELAXED,
                                    __HIP_MEMORY_SCOPE_AGENT);
        }

        // ---- deferred output write (drains during next step's wait)
        {
            f32x2 ov = { o2[0], o2[1] };
            *(f32x2*)&out[(size_t)t * (NB * NHID) + (size_t)b * NHID + ks + kl] = ov;
        }
    }

    // ---- h_last output
    {
        int idx = tid * 2;
        int b = idx >> 4, kl = idx & 15;
        float* hl = out + (size_t)TT * NB * NHID;
        f32x2 hv = { h_lds[b][kl], h_lds[b][kl + 1] };
        *(f32x2*)&hl[(size_t)b * NHID + ks + kl] = hv;
    }
}

extern "C" void kernel_launch(void* const* d_in, const int* in_sizes, int n_in,
                              void* d_out, int out_size, void* d_ws, size_t ws_size,
                              hipStream_t stream) {
    const float* X   = (const float*)d_in[0];
    const float* h0  = (const float*)d_in[1];
    const float* Wih = (const float*)d_in[2];
    const float* Whh = (const float*)d_in[3];
    const float* bih = (const float*)d_in[4];
    const float* bhh = (const float*)d_in[5];
    const float* Wd  = (const float*)d_in[6];
    const float* bd  = (const float*)d_in[7];
    float* out = (float*)d_out;

    init_flags_k<<<dim3(1), dim3(64), 0, stream>>>();

    gru_persist<<<dim3(256), dim3(256), 0, stream>>>(
        X, h0, Wih, Whh, bih, bhh, Wd, bd, out);
}

// Round 10
// 17040.945 us; speedup vs baseline: 1.6428x; 1.1075x over previous
//
#include <hip/hip_runtime.h>

#define TT   2048
#define NB   32
#define NI   512
#define NHID 512
#define NWG  32
#define KSL  16   // h-columns owned per workgroup

typedef float    f32x4 __attribute__((ext_vector_type(4)));
typedef float    f32x2 __attribute__((ext_vector_type(2)));
typedef _Float16 f16x8 __attribute__((ext_vector_type(8)));

// flags[0..63]: flags[2w+half] = t+1 when (block w, batch-half) h-slice stored.
// flags[64] = xcc mask, flags[65] = arrival count (placement check).
__device__ __align__(256) unsigned int g_flags[80];
__device__ __align__(256) _Float16    g_hb0[NB * NHID];
__device__ __align__(256) _Float16    g_hb1[NB * NHID];

__device__ __forceinline__ f16x8 pack8(f32x4 a, f32x4 b) {
    f16x8 r;
    r[0] = (_Float16)a[0]; r[1] = (_Float16)a[1]; r[2] = (_Float16)a[2]; r[3] = (_Float16)a[3];
    r[4] = (_Float16)b[0]; r[5] = (_Float16)b[1]; r[6] = (_Float16)b[2]; r[7] = (_Float16)b[3];
    return r;
}

__device__ __forceinline__ unsigned int poll_load_nt(const unsigned int* p) {
    unsigned int v;
    asm volatile("global_load_dword %0, %1, off nt\n\ts_waitcnt vmcnt(0)"
                 : "=v"(v) : "v"(p) : "memory");
    return v;
}

extern "C" __global__ void init_flags_k() {
    if (threadIdx.x < 80) g_flags[threadIdx.x] = 0u;
}

// ZERO-BARRIER persistent GRU. 32 worker blocks (bid%8==0 -> XCD0), 4 waves:
//   waves 0/1 = CONSUMERS (half = batches 0-15 / 16-31): the serial chain.
//     poll 32 per-half flags -> nt h load -> 48 MFMA -> IN-REGISTER gates
//     (D-frag: lane holds batch=lane&15, k=(lane>>4)*4+reg -> gi read f32x4,
//      h_old kept in 4 VGPRs) -> 8B h store + 16B out store -> vmcnt -> flag.
//   waves 2/3 = PRODUCERS: compute gi(r,z,n)+dense for step tp into a 2-deep
//     parity LDS buffer, up to 2 steps ahead (X HBM latency off critical path),
//     synced via LDS seq counters (write->lgkmcnt(0)->flag; poll->read).
// No __syncthreads in the loop. No LDS round-trip for gh.
extern "C" __global__ void __launch_bounds__(256, 1)
gru_persist(const float* __restrict__ X, const float* __restrict__ h0,
            const float* __restrict__ Wih, const float* __restrict__ Whh,
            const float* __restrict__ bih, const float* __restrict__ bhh,
            const float* __restrict__ Wd,  const float* __restrict__ bd,
            float* __restrict__ out)
{
    if (blockIdx.x & 7) return;
    const int w  = blockIdx.x >> 3;
    const int ks = w * KSL;

    __shared__ float gi_lds[2][2][4][16][16]; // [parity][half][r,z,n,dense][b_loc][k_loc]
    __shared__ float bias_h[3][KSL];          // bhh r,z,n (own k)
    __shared__ float bias_i[4][KSL];          // bih r,z,n + b_dense (own k)
    __shared__ unsigned int seq[4];           // [half]=prod_seq, [2+half]=cons_seq
    __shared__ unsigned int fast_sh;
    volatile unsigned int* vseq = seq;

    const int tid  = threadIdx.x;
    const int lane = tid & 63;
    const int wv   = tid >> 6;
    const int half = wv & 1;
    const int isp  = wv >> 1;      // 1 = producer
    const int r15  = lane & 15;
    const int g4   = lane >> 4;

    if (tid < 4) seq[tid] = 0u;
    if (tid < KSL) {
        int k = ks + tid;
        bias_h[0][tid] = bhh[k];
        bias_h[1][tid] = bhh[512 + k];
        bias_h[2][tid] = bhh[1024 + k];
        bias_i[0][tid] = bih[k];
        bias_i[1][tid] = bih[512 + k];
        bias_i[2][tid] = bih[1024 + k];
        bias_i[3][tid] = bd[k];
    }
    if (tid == 0) {
        unsigned int xcc;
        asm volatile("s_getreg_b32 %0, hwreg(HW_REG_XCC_ID, 0, 32)" : "=s"(xcc));
        unsigned int bit = 1u << (xcc & 7);
        unsigned int* mask  = g_flags + 64;
        unsigned int* count = g_flags + 65;
        unsigned int old = __hip_atomic_fetch_or(mask, bit, __ATOMIC_RELAXED,
                                                 __HIP_MEMORY_SCOPE_AGENT);
        asm volatile("" :: "v"(old));
        __hip_atomic_fetch_add(count, 1u, __ATOMIC_RELAXED, __HIP_MEMORY_SCOPE_AGENT);
        while (__hip_atomic_load(count, __ATOMIC_RELAXED,
                                 __HIP_MEMORY_SCOPE_AGENT) < NWG) { }
        unsigned int m = __hip_atomic_load(mask, __ATOMIC_RELAXED,
                                           __HIP_MEMORY_SCOPE_AGENT);
        fast_sh = ((m & (m - 1)) == 0) ? 1u : 0u;
    }
    __syncthreads();
    const bool fast = (fast_sh != 0);

    if (!isp) {
        // ================= CONSUMER (waves 0,1) =================
        __builtin_amdgcn_s_setprio(1);
        const int bg = half * 16 + r15;            // my batch (via D col / B row)

        f16x8 A[3][16];                            // Whh fragments, rows ks+r15
        #pragma unroll
        for (int q = 0; q < 3; ++q) {
            const float* src = Whh + (size_t)(q * 512 + ks + r15) * NHID;
            #pragma unroll
            for (int kc = 0; kc < 16; ++kc) {
                const f32x4* p = (const f32x4*)(src + kc * 32 + g4 * 8);
                A[q][kc] = pack8(p[0], p[1]);
            }
        }
        f32x4 hold = *(const f32x4*)(h0 + (size_t)bg * NHID + ks + g4 * 4);
        const f32x4 bhr = *(const f32x4*)&bias_h[0][g4 * 4];
        const f32x4 bhz = *(const f32x4*)&bias_h[1][g4 * 4];
        const f32x4 bhn = *(const f32x4*)&bias_h[2][g4 * 4];
        const f32x4 bir = *(const f32x4*)&bias_i[0][g4 * 4];
        const f32x4 biz = *(const f32x4*)&bias_i[1][g4 * 4];
        const f32x4 bin = *(const f32x4*)&bias_i[2][g4 * 4];
        const f32x4 bd4 = *(const f32x4*)&bias_i[3][g4 * 4];

        const float* h0row = h0 + (size_t)bg * NHID;

        #pragma unroll 1
        for (int t = 0; t < TT; ++t) {
            // -- 1. cross-block wait: the 32 flags of MY half
            if (t > 0 && lane < NWG) {
                const unsigned int* fp = &g_flags[2 * lane + half];
                if (fast) { while (poll_load_nt(fp) < (unsigned)t) { } }
                else      { while (__hip_atomic_load(fp, __ATOMIC_RELAXED,
                                       __HIP_MEMORY_SCOPE_AGENT) < (unsigned)t) { } }
            }
            // -- 2. load h_t fragment
            f16x8 Bf[16];
            if (t == 0) {
                #pragma unroll
                for (int kc = 0; kc < 16; ++kc) {
                    const f32x4* p = (const f32x4*)(h0row + kc * 32 + g4 * 8);
                    Bf[kc] = pack8(p[0], p[1]);
                }
            } else {
                const _Float16* hrow = ((t & 1) ? g_hb1 : g_hb0) + (size_t)bg * NHID;
                if (fast) {
                    #pragma unroll
                    for (int kc = 0; kc < 16; ++kc) {
                        const _Float16* p = hrow + kc * 32 + g4 * 8;
                        asm volatile("global_load_dwordx4 %0, %1, off nt"
                                     : "=v"(Bf[kc]) : "v"(p));
                    }
                } else {
                    #pragma unroll
                    for (int kc = 0; kc < 16; ++kc) {
                        const _Float16* p = hrow + kc * 32 + g4 * 8;
                        asm volatile("global_load_dwordx4 %0, %1, off sc0 sc1"
                                     : "=v"(Bf[kc]) : "v"(p));
                    }
                }
                asm volatile("s_waitcnt vmcnt(0)" ::: "memory");
                __builtin_amdgcn_sched_barrier(0);
            }
            // -- 3. gh MFMA (acc[reg] = gh[k=ks+g4*4+reg][b=bg])
            f32x4 a0 = {0.f,0.f,0.f,0.f}, a1 = a0, a2 = a0;
            #pragma unroll
            for (int kc = 0; kc < 16; ++kc) {
                a0 = __builtin_amdgcn_mfma_f32_16x16x32_f16(A[0][kc], Bf[kc], a0, 0, 0, 0);
                a1 = __builtin_amdgcn_mfma_f32_16x16x32_f16(A[1][kc], Bf[kc], a1, 0, 0, 0);
                a2 = __builtin_amdgcn_mfma_f32_16x16x32_f16(A[2][kc], Bf[kc], a2, 0, 0, 0);
            }
            // -- 4. gi ready? read it, release the parity slot
            while (vseq[half] < (unsigned)(t + 1)) { }
            const int par = t & 1;
            f32x4 gr = *(const f32x4*)&gi_lds[par][half][0][r15][g4 * 4];
            f32x4 gz = *(const f32x4*)&gi_lds[par][half][1][r15][g4 * 4];
            f32x4 gn = *(const f32x4*)&gi_lds[par][half][2][r15][g4 * 4];
            f32x4 gd = *(const f32x4*)&gi_lds[par][half][3][r15][g4 * 4];
            asm volatile("s_waitcnt lgkmcnt(0)" ::: "memory");
            if (lane == 0) vseq[2 + half] = (unsigned)(t + 1);
            // -- 5. gates in-register
            f32x4 hn, o;
            #pragma unroll
            for (int i = 0; i < 4; ++i) {
                float rr = 1.f / (1.f + __expf(-((gr[i] + bir[i]) + (a0[i] + bhr[i]))));
                float zz = 1.f / (1.f + __expf(-((gz[i] + biz[i]) + (a1[i] + bhz[i]))));
                float aa = (gn[i] + bin[i]) + rr * (a2[i] + bhn[i]);
                float nn = 1.f - 2.f / (__expf(2.f * aa) + 1.f);
                hn[i] = (1.f - zz) * nn + zz * hold[i];
                o[i]  = hn[i] + gd[i] + bd4[i];
            }
            hold = hn;
            // -- 6. h broadcast store (4 fp16 = 8B, consecutive k)
            union { _Float16 h[4]; unsigned long long u; } cv;
            cv.h[0] = (_Float16)hn[0]; cv.h[1] = (_Float16)hn[1];
            cv.h[2] = (_Float16)hn[2]; cv.h[3] = (_Float16)hn[3];
            _Float16* hw = (((t + 1) & 1) ? g_hb1 : g_hb0) + (size_t)bg * NHID + ks + g4 * 4;
            if (fast) {
                *(unsigned long long*)hw = cv.u;
            } else {
                asm volatile("global_store_dwordx2 %0, %1, off sc0 sc1"
                             :: "v"(hw), "v"(cv.u) : "memory");
            }
            // -- 7. drain h store, publish own flag
            asm volatile("s_waitcnt vmcnt(0)" ::: "memory");
            if (lane == 0) {
                unsigned int* fp = &g_flags[2 * w + half];
                if (fast) *(volatile unsigned int*)fp = (unsigned)(t + 1);
                else __hip_atomic_store(fp, (unsigned)(t + 1), __ATOMIC_RELAXED,
                                        __HIP_MEMORY_SCOPE_AGENT);
            }
            // -- 8. output store (off critical path, drains later)
            *(f32x4*)(out + (size_t)t * (NB * NHID) + (size_t)bg * NHID + ks + g4 * 4) = o;
        }
        // h_last
        *(f32x4*)(out + (size_t)TT * (NB * NHID) + (size_t)bg * NHID + ks + g4 * 4) = hold;
    } else {
        // ================= PRODUCER (waves 2,3) =================
        f16x8 A[4][16];                            // Wih r,z,n + Wd, rows ks+r15
        #pragma unroll
        for (int q = 0; q < 4; ++q) {
            const float* src = (q < 3) ? (Wih + (size_t)(q * 512 + ks + r15) * NI)
                                       : (Wd  + (size_t)(ks + r15) * NI);
            #pragma unroll
            for (int kc = 0; kc < 16; ++kc) {
                const f32x4* p = (const f32x4*)(src + kc * 32 + g4 * 8);
                A[q][kc] = pack8(p[0], p[1]);
            }
        }
        const float* Xrow = X + (size_t)(half * 16 + r15) * NI;

        #pragma unroll 1
        for (int tp = 0; tp < TT; ++tp) {
            // throttle: 2-deep buffer -> need consumer to have consumed tp-2
            while ((int)vseq[2 + half] < tp - 1) { }
            const float* xp = Xrow + (size_t)tp * (NB * NI);
            f16x8 Bf[16];
            #pragma unroll
            for (int kc = 0; kc < 16; ++kc) {
                const f32x4* p = (const f32x4*)(xp + kc * 32 + g4 * 8);
                Bf[kc] = pack8(p[0], p[1]);
            }
            f32x4 a0 = {0.f,0.f,0.f,0.f}, a1 = a0, a2 = a0, a3 = a0;
            #pragma unroll
            for (int kc = 0; kc < 16; ++kc) {
                a0 = __builtin_amdgcn_mfma_f32_16x16x32_f16(A[0][kc], Bf[kc], a0, 0, 0, 0);
                a1 = __builtin_amdgcn_mfma_f32_16x16x32_f16(A[1][kc], Bf[kc], a1, 0, 0, 0);
                a2 = __builtin_amdgcn_mfma_f32_16x16x32_f16(A[2][kc], Bf[kc], a2, 0, 0, 0);
                a3 = __builtin_amdgcn_mfma_f32_16x16x32_f16(A[3][kc], Bf[kc], a3, 0, 0, 0);
            }
            const int par = tp & 1;
            *(f32x4*)&gi_lds[par][half][0][r15][g4 * 4] = a0;
            *(f32x4*)&gi_lds[par][half][1][r15][g4 * 4] = a1;
            *(f32x4*)&gi_lds[par][half][2][r15][g4 * 4] = a2;
            *(f32x4*)&gi_lds[par][half][3][r15][g4 * 4] = a3;
            asm volatile("s_waitcnt lgkmcnt(0)" ::: "memory");
            if (lane == 0) vseq[half] = (unsigned)(tp + 1);
        }
    }
}

extern "C" void kernel_launch(void* const* d_in, const int* in_sizes, int n_in,
                              void* d_out, int out_size, void* d_ws, size_t ws_size,
                              hipStream_t stream) {
    const float* X   = (const float*)d_in[0];
    const float* h0  = (const float*)d_in[1];
    const float* Wih = (const float*)d_in[2];
    const float* Whh = (const float*)d_in[3];
    const float* bih = (const float*)d_in[4];
    const float* bhh = (const float*)d_in[5];
    const float* Wd  = (const float*)d_in[6];
    const float* bd  = (const float*)d_in[7];
    float* out = (float*)d_out;

    init_flags_k<<<dim3(1), dim3(128), 0, stream>>>();

    gru_persist<<<dim3(256), dim3(256), 0, stream>>>(
        X, h0, Wih, Whh, bih, bhh, Wd, bd, out);
}